// Round 8
// baseline (334.380 us; speedup 1.0000x reference)
//
#include <hip/hip_runtime.h>
#include <hip/hip_bf16.h>

#define NEG_SLOPE 0.2f
#define BSHIFT 8                 // 256 dsts per bucket
#define BSIZE  (1 << BSHIFT)
#define CAP    10240             // pairs capacity per bucket (mean ~8192, +22 sigma)
#define SRC_MASK 0x1FFFF         // 17 bits for src id (n < 131072)
#define NBMAX 400

__device__ __forceinline__ float lrelu(float x) { return x >= 0.f ? x : NEG_SLOPE * x; }
__device__ __forceinline__ unsigned short f2bf(float f) {
    unsigned u = __float_as_uint(f);
    return (unsigned short)((u + 0x7fffu + ((u >> 16) & 1u)) >> 16);  // RNE
}

// Pass 1: h = A @ W (wave per row) -> h16 (bf16), fused s_i = h.a_i, s_j = h.a_j
__global__ __launch_bounds__(256) void k_gemm(
    const float* __restrict__ A, const float* __restrict__ W,
    const float* __restrict__ att,
    unsigned short* __restrict__ h16, float* __restrict__ s_i, float* __restrict__ s_j, int n)
{
    __shared__ float Wl[64 * 64];
    __shared__ float Al[4][64];
    int tid = threadIdx.x;
    for (int t = tid; t < 64 * 64; t += 256) Wl[t] = W[t];
    int wave = tid >> 6, lane = tid & 63;
    int row = blockIdx.x * 4 + wave;
    float a_val = 0.f;
    if (row < n) a_val = A[(long)row * 64 + lane];
    Al[wave][lane] = a_val;
    __syncthreads();
    if (row >= n) return;

    float acc = 0.f;
#pragma unroll
    for (int k = 0; k < 64; ++k)
        acc = fmaf(Al[wave][k], Wl[k * 64 + lane], acc);

    h16[(long)row * 64 + lane] = f2bf(acc);

    float vi = acc * att[lane];
    float vj = acc * att[64 + lane];
#pragma unroll
    for (int off = 32; off; off >>= 1) {
        vi += __shfl_xor(vi, off, 64);
        vj += __shfl_xor(vj, off, 64);
    }
    if (lane == 0) { s_i[row] = vi; s_j[row] = vj; }
}

// Bin step A: count per bucket in LDS, reserve global bucket space, emit packed pairs.
__global__ __launch_bounds__(256) void k_binA(
    const int* __restrict__ edges, int* __restrict__ bcursor,
    unsigned* __restrict__ pairs, int n_edges, int nb)
{
    __shared__ int hist[NBMAX];
    __shared__ int cur[NBMAX];
    int t = threadIdx.x;
    for (int b = t; b < nb; b += 256) hist[b] = 0;
    __syncthreads();
    long base = (long)blockIdx.x * 8192;

    for (int k = 0; k < 32; ++k) {
        long e = base + k * 256 + t;
        if (e < n_edges) {
            int d = edges[e];
            int i = (int)(e >> 5);
            if (d != i) atomicAdd(&hist[d >> BSHIFT], 1);
        }
    }
    __syncthreads();

    for (int b = t; b < nb; b += 256) {
        int c = hist[b];
        int g = 0;
        if (c) g = atomicAdd(&bcursor[b], c);
        cur[b] = b * CAP + g;
    }
    __syncthreads();

    for (int k = 0; k < 32; ++k) {
        long e = base + k * 256 + t;
        if (e < n_edges) {
            int d = edges[e];
            int i = (int)(e >> 5);
            if (d != i) {
                int b = d >> BSHIFT;
                int slot = atomicAdd(&cur[b], 1);
                if (slot < (b + 1) * CAP)
                    pairs[slot] = ((unsigned)(d & (BSIZE - 1)) << 17) | (unsigned)i;
            }
        }
    }
}

// Bin step B: one block per bucket (391 blocks, 43 KB LDS -> 3 blocks/CU).
__global__ __launch_bounds__(512) void k_binB(
    const int* __restrict__ bcursor, unsigned* __restrict__ pairs,
    int* __restrict__ offs, int* __restrict__ counts, int n)
{
    __shared__ unsigned pl[CAP];         // 40 KB
    __shared__ int hist[BSIZE];
    __shared__ int scn[BSIZE];
    __shared__ int cur[BSIZE];
    int b = blockIdx.x, t = threadIdx.x;
    int cnt = bcursor[b];
    if (cnt > CAP) cnt = CAP;
    long wb = (long)b * CAP;

    for (int s = t; s < cnt; s += 512) pl[s] = pairs[wb + s];
    if (t < BSIZE) hist[t] = 0;
    __syncthreads();
    for (int s = t; s < cnt; s += 512) atomicAdd(&hist[pl[s] >> 17], 1);
    __syncthreads();

    if (t < BSIZE) scn[t] = hist[t];
    __syncthreads();
    for (int d = 1; d < BSIZE; d <<= 1) {
        int v = 0;
        if (t < BSIZE && t >= d) v = scn[t - d];
        __syncthreads();
        if (t < BSIZE) scn[t] += v;
        __syncthreads();
    }
    if (t < BSIZE) {
        int start = scn[t] - hist[t];
        int dg = (b << BSHIFT) + t;
        if (dg < n) {
            offs[dg] = (int)(wb + start);
            counts[dg] = hist[t];
        }
        cur[t] = start;
    }
    __syncthreads();

    for (int s = t; s < cnt; s += 512) {
        unsigned pk = pl[s];
        int dl = pk >> 17;
        int pos = atomicAdd(&cur[dl], 1);
        ((int*)pairs)[wb + pos] = (int)(pk & SRC_MASK);
    }
}

// Gather: wave per dst, half-wave per edge, u32 loads (2 bf16 features/lane).
__global__ __launch_bounds__(256) void k_gather(
    const int* __restrict__ offs, const int* __restrict__ counts,
    const int* __restrict__ srcl, const unsigned* __restrict__ h32,
    const float* __restrict__ s_i, const float* __restrict__ s_j,
    const float* __restrict__ bias, float* __restrict__ out, int n)
{
    int gw = (blockIdx.x * 256 + threadIdx.x) >> 6;
    int lane = threadIdx.x & 63;
    if (gw >= n) return;
    int d = gw;
    int off = offs[d], deg = counts[d];
    int half = lane >> 5, fl = lane & 31;
    float si = s_i[d];
    float es = __expf(lrelu(si + s_j[d]));   // self-loop weight

    float ax = 0.f, ay = 0.f, denp = 0.f;
    for (int base = 0; base < deg; base += 64) {
        int t = base + lane;
        int cnt = min(64, deg - base);
        int s = 0; float w = 0.f;
        if (t < deg) {
            s = srcl[off + t];
            w = __expf(lrelu(si + s_j[s]));
        }
        denp += w;
        for (int j = 0; j < cnt; j += 2) {
            int idx = j + half;
            int sel = (idx < cnt) ? idx : j;
            int   se = __shfl(s, sel, 64);
            float we = __shfl(w, sel, 64);
            if (idx >= cnt) we = 0.f;
            unsigned pk = h32[((unsigned)se << 5) | fl];
            ax = fmaf(__uint_as_float(pk << 16), we, ax);
            ay = fmaf(__uint_as_float(pk & 0xffff0000u), we, ay);
        }
    }

    // combine the two half-wave partial sums
    ax += __shfl_xor(ax, 32, 64);
    ay += __shfl_xor(ay, 32, 64);
#pragma unroll
    for (int o = 32; o; o >>= 1) denp += __shfl_xor(denp, o, 64);

    // self loop + epilogue
    unsigned pk = h32[((unsigned)d << 5) | fl];
    ax = fmaf(__uint_as_float(pk << 16), es, ax);
    ay = fmaf(__uint_as_float(pk & 0xffff0000u), es, ay);
    float den = denp + es + 1e-16f;
    float2 bb = ((const float2*)bias)[fl];
    float vx = ax / den + bb.x;
    float vy = ay / den + bb.y;
    float sq = vx * vx + vy * vy;
#pragma unroll
    for (int o = 16; o; o >>= 1) sq += __shfl_xor(sq, o, 64);  // sum within 32-group
    float inv = 1.f / fmaxf(sqrtf(sq), 1e-12f);
    if (half == 0) {
        float2 v2 = make_float2(vx * inv, vy * inv);
        ((float2*)out)[(long)d * 32 + fl] = v2;
    }
}

extern "C" void kernel_launch(void* const* d_in, const int* in_sizes, int n_in,
                              void* d_out, int out_size, void* d_ws, size_t ws_size,
                              hipStream_t stream)
{
    const float* A    = (const float*)d_in[0]; // all_embed (n,64) f32
    const float* W    = (const float*)d_in[1]; // (64,64) f32
    const float* att  = (const float*)d_in[2]; // (128,) f32
    const float* bias = (const float*)d_in[3]; // (64,) f32
    const int* edges  = (const int*)d_in[7];   // (n,32) int32

    int n = in_sizes[0] / 64;          // 100000
    int n_edges = in_sizes[7];         // n * 32
    int nb = (n + BSIZE - 1) >> BSHIFT; // 391 buckets

    // workspace layout
    unsigned short* h16 = (unsigned short*)d_ws;    // n*64 bf16
    float* s_i      = (float*)(h16 + (long)n * 64); // n
    float* s_j      = s_i + n;                      // n
    int* offs       = (int*)(s_j + n);              // n
    int* counts     = offs + n;                     // n
    int* bcursor    = counts + n;                   // 512
    unsigned* pairs = (unsigned*)(bcursor + 512);   // nb*CAP (aliased as srcl after binB)

    (void)hipMemsetAsync(bcursor, 0, 512 * sizeof(int), stream);

    int blocks_rows = (n + 3) / 4;
    k_gemm<<<blocks_rows, 256, 0, stream>>>(A, W, att, h16, s_i, s_j, n);

    int blocks_binA = (n_edges + 8191) / 8192;
    k_binA<<<blocks_binA, 256, 0, stream>>>(edges, bcursor, pairs, n_edges, nb);

    k_binB<<<nb, 512, 0, stream>>>(bcursor, pairs, offs, counts, n);

    int blocks_waves = ((long)n * 64 + 255) / 256;  // wave per dst
    k_gather<<<blocks_waves, 256, 0, stream>>>(offs, counts, (const int*)pairs,
                                               (const unsigned*)h16,
                                               s_i, s_j, bias, (float*)d_out, n);
}

// Round 9
// 304.084 us; speedup vs baseline: 1.0996x; 1.0996x over previous
//
#include <hip/hip_runtime.h>
#include <hip/hip_bf16.h>

#define NEG_SLOPE 0.2f
#define BSHIFT 9                 // 512 dsts per bucket
#define BSIZE  (1 << BSHIFT)
#define CAP    20480             // pairs capacity per bucket (mean ~16384, +32 sigma)
#define SRC_MASK 0x1FFFF         // 17 bits for src id (n < 131072)

__device__ __forceinline__ float lrelu(float x) { return x >= 0.f ? x : NEG_SLOPE * x; }
__device__ __forceinline__ float bf2f(unsigned short u) {
    return __uint_as_float((unsigned)u << 16);
}
__device__ __forceinline__ unsigned short f2bf(float f) {
    unsigned u = __float_as_uint(f);
    return (unsigned short)((u + 0x7fffu + ((u >> 16) & 1u)) >> 16);  // RNE
}

// Pass 1: h = A @ W (wave per row) -> h16 (bf16), fused s_i = h.a_i, s_j = h.a_j
__global__ __launch_bounds__(256) void k_gemm(
    const float* __restrict__ A, const float* __restrict__ W,
    const float* __restrict__ att,
    unsigned short* __restrict__ h16, float* __restrict__ s_i, float* __restrict__ s_j, int n)
{
    __shared__ float Wl[64 * 64];
    __shared__ float Al[4][64];
    int tid = threadIdx.x;
    for (int t = tid; t < 64 * 64; t += 256) Wl[t] = W[t];
    int wave = tid >> 6, lane = tid & 63;
    int row = blockIdx.x * 4 + wave;
    float a_val = 0.f;
    if (row < n) a_val = A[(long)row * 64 + lane];
    Al[wave][lane] = a_val;
    __syncthreads();
    if (row >= n) return;

    // 4 partial accumulators: breaks the serial FMA dependence chain
    float a0 = 0.f, a1 = 0.f, a2 = 0.f, a3 = 0.f;
#pragma unroll
    for (int k = 0; k < 64; k += 4) {
        a0 = fmaf(Al[wave][k],     Wl[(k)     * 64 + lane], a0);
        a1 = fmaf(Al[wave][k + 1], Wl[(k + 1) * 64 + lane], a1);
        a2 = fmaf(Al[wave][k + 2], Wl[(k + 2) * 64 + lane], a2);
        a3 = fmaf(Al[wave][k + 3], Wl[(k + 3) * 64 + lane], a3);
    }
    float acc = (a0 + a1) + (a2 + a3);

    h16[(long)row * 64 + lane] = f2bf(acc);

    float vi = acc * att[lane];
    float vj = acc * att[64 + lane];
#pragma unroll
    for (int off = 32; off; off >>= 1) {
        vi += __shfl_xor(vi, off, 64);
        vj += __shfl_xor(vj, off, 64);
    }
    if (lane == 0) { s_i[row] = vi; s_j[row] = vj; }
}

// Bin step A: count per bucket in LDS, reserve global bucket space, emit packed pairs.
__global__ __launch_bounds__(256) void k_binA(
    const int* __restrict__ edges, int* __restrict__ bcursor,
    unsigned* __restrict__ pairs, int n_edges, int nb)
{
    __shared__ int hist[256];
    __shared__ int cur[256];
    int t = threadIdx.x;
    hist[t] = 0;
    __syncthreads();
    long base = (long)blockIdx.x * 8192;

    for (int k = 0; k < 32; ++k) {
        long e = base + k * 256 + t;
        if (e < n_edges) {
            int d = edges[e];
            int i = (int)(e >> 5);
            if (d != i) atomicAdd(&hist[d >> BSHIFT], 1);
        }
    }
    __syncthreads();

    if (t < nb) {
        int c = hist[t];
        int g = 0;
        if (c) g = atomicAdd(&bcursor[t], c);
        cur[t] = t * CAP + g;
    }
    __syncthreads();

    for (int k = 0; k < 32; ++k) {
        long e = base + k * 256 + t;
        if (e < n_edges) {
            int d = edges[e];
            int i = (int)(e >> 5);
            if (d != i) {
                int b = d >> BSHIFT;
                int slot = atomicAdd(&cur[b], 1);
                if (slot < (b + 1) * CAP)
                    pairs[slot] = ((unsigned)(d & (BSIZE - 1)) << 17) | (unsigned)i;
            }
        }
    }
}

// Bin step B (staging-free): hist+scan in 6 KB LDS, re-read pairs (L2-hot) and
// scatter src ids into a SEPARATE srcl buffer. One block per bucket.
__global__ __launch_bounds__(512) void k_binB(
    const int* __restrict__ bcursor, const unsigned* __restrict__ pairs,
    int* __restrict__ srcl, int* __restrict__ offs, int* __restrict__ counts, int n)
{
    __shared__ int hist[BSIZE];
    __shared__ int scn[BSIZE];
    __shared__ int cur[BSIZE];
    int b = blockIdx.x, t = threadIdx.x;
    int cnt = bcursor[b];
    if (cnt > CAP) cnt = CAP;
    long wb = (long)b * CAP;

    hist[t] = 0;
    __syncthreads();
    for (int s = t; s < cnt; s += 512) atomicAdd(&hist[pairs[wb + s] >> 17], 1);
    __syncthreads();

    scn[t] = hist[t];
    __syncthreads();
    for (int d = 1; d < BSIZE; d <<= 1) {
        int v = (t >= d) ? scn[t - d] : 0;
        __syncthreads();
        scn[t] += v;
        __syncthreads();
    }
    int start = scn[t] - hist[t];
    int dg = (b << BSHIFT) + t;
    if (dg < n) {
        offs[dg] = (int)(wb + start);
        counts[dg] = hist[t];
    }
    cur[t] = start;
    __syncthreads();

    for (int s = t; s < cnt; s += 512) {
        unsigned pk = pairs[wb + s];
        int pos = atomicAdd(&cur[pk >> 17], 1);
        srcl[wb + pos] = (int)(pk & SRC_MASK);
    }
}

// Gather (R7 form): wave per dst, uniform-index broadcast, 4-edge unroll.
__global__ __launch_bounds__(256) void k_gather(
    const int* __restrict__ offs, const int* __restrict__ counts,
    const int* __restrict__ srcl, const unsigned short* __restrict__ h16,
    const float* __restrict__ s_i, const float* __restrict__ s_j,
    const float* __restrict__ bias, float* __restrict__ out, int n)
{
    int gw = (blockIdx.x * 256 + threadIdx.x) >> 6;
    int lane = threadIdx.x & 63;
    if (gw >= n) return;
    int d = gw;
    int off = offs[d], deg = counts[d];
    float si = s_i[d];
    float es = __expf(lrelu(si + s_j[d]));   // self-loop weight

    float acc = 0.f, denp = 0.f;
    for (int base = 0; base < deg; base += 64) {
        int t = base + lane;
        int cnt = min(64, deg - base);
        int s = 0; float w = 0.f;
        if (t < deg) {
            s = srcl[off + t];
            w = __expf(lrelu(si + s_j[s]));
        }
        denp += w;
        int j = 0;
        for (; j + 4 <= cnt; j += 4) {
            int   s0 = __shfl(s, j, 64),     s1 = __shfl(s, j + 1, 64);
            int   s2 = __shfl(s, j + 2, 64), s3 = __shfl(s, j + 3, 64);
            float w0 = __shfl(w, j, 64),     w1 = __shfl(w, j + 1, 64);
            float w2 = __shfl(w, j + 2, 64), w3 = __shfl(w, j + 3, 64);
            float h0 = bf2f(h16[(unsigned)(s0 << 6) | lane]);
            float h1 = bf2f(h16[(unsigned)(s1 << 6) | lane]);
            float h2 = bf2f(h16[(unsigned)(s2 << 6) | lane]);
            float h3 = bf2f(h16[(unsigned)(s3 << 6) | lane]);
            acc = fmaf(h0, w0, acc); acc = fmaf(h1, w1, acc);
            acc = fmaf(h2, w2, acc); acc = fmaf(h3, w3, acc);
        }
        for (; j < cnt; ++j) {
            int   ss = __shfl(s, j, 64);
            float ww = __shfl(w, j, 64);
            acc = fmaf(bf2f(h16[(unsigned)(ss << 6) | lane]), ww, acc);
        }
    }

#pragma unroll
    for (int o = 32; o; o >>= 1) denp += __shfl_xor(denp, o, 64);

    float hd = bf2f(h16[(unsigned)(d << 6) | lane]);
    acc = fmaf(hd, es, acc);
    float den = denp + es + 1e-16f;
    float v = acc / den + bias[lane];
    float sq = v * v;
#pragma unroll
    for (int o = 32; o; o >>= 1) sq += __shfl_xor(sq, o, 64);
    v = v / fmaxf(sqrtf(sq), 1e-12f);
    out[(long)d * 64 + lane] = v;
}

extern "C" void kernel_launch(void* const* d_in, const int* in_sizes, int n_in,
                              void* d_out, int out_size, void* d_ws, size_t ws_size,
                              hipStream_t stream)
{
    const float* A    = (const float*)d_in[0]; // all_embed (n,64) f32
    const float* W    = (const float*)d_in[1]; // (64,64) f32
    const float* att  = (const float*)d_in[2]; // (128,) f32
    const float* bias = (const float*)d_in[3]; // (64,) f32
    const int* edges  = (const int*)d_in[7];   // (n,32) int32

    int n = in_sizes[0] / 64;          // 100000
    int n_edges = in_sizes[7];         // n * 32
    int nb = (n + BSIZE - 1) >> BSHIFT; // 196 buckets

    // workspace layout (~48 MB)
    unsigned short* h16 = (unsigned short*)d_ws;    // n*64 bf16      12.8 MB
    float* s_i      = (float*)(h16 + (long)n * 64); // n
    float* s_j      = s_i + n;                      // n
    int* offs       = (int*)(s_j + n);              // n
    int* counts     = offs + n;                     // n
    int* bcursor    = counts + n;                   // 512
    unsigned* pairs = (unsigned*)(bcursor + 512);   // nb*CAP         16.05 MB
    int* srcl       = (int*)(pairs + (long)nb * CAP); // nb*CAP       16.05 MB

    (void)hipMemsetAsync(bcursor, 0, 512 * sizeof(int), stream);

    int blocks_rows = (n + 3) / 4;
    k_gemm<<<blocks_rows, 256, 0, stream>>>(A, W, att, h16, s_i, s_j, n);

    int blocks_binA = (n_edges + 8191) / 8192;
    k_binA<<<blocks_binA, 256, 0, stream>>>(edges, bcursor, pairs, n_edges, nb);

    k_binB<<<nb, 512, 0, stream>>>(bcursor, pairs, srcl, offs, counts, n);

    int blocks_waves = ((long)n * 64 + 255) / 256;  // wave per dst
    k_gather<<<blocks_waves, 256, 0, stream>>>(offs, counts, srcl, h16,
                                               s_i, s_j, bias, (float*)d_out, n);
}